// Round 1
// 415.057 us; speedup vs baseline: 1.0118x; 1.0118x over previous
//
#include <hip/hip_runtime.h>
#include <hip/hip_bf16.h>

#define NN 50000
#define EE 1000000
static constexpr float EPSV = 1e-3f;
static constexpr float FIXSCALE = 16777216.f;  // 2^24

typedef __attribute__((ext_vector_type(8))) short short8;
typedef __attribute__((ext_vector_type(4))) float fx4;

__device__ inline float blo(unsigned u) { return __uint_as_float(u << 16); }
__device__ inline float bhi(unsigned u) { return __uint_as_float(u & 0xffff0000u); }
__device__ inline unsigned short f2b(float f) {
    __hip_bfloat16 h = __float2bfloat16(f);
    return *(unsigned short*)&h;
}
__device__ inline unsigned pack2(float a, float b) {
    return (unsigned)f2b(a) | ((unsigned)f2b(b) << 16);
}

// async global->LDS DMA, 16 B per lane
__device__ inline void gload_lds16(const unsigned short* g, unsigned short* ldsbase) {
    __builtin_amdgcn_global_load_lds(
        (const __attribute__((address_space(1))) unsigned int*)(const void*)g,
        (__attribute__((address_space(3))) unsigned int*)(void*)ldsbase, 16, 0, 0);
}

// ---------------- setup: zero cnt64 + weight transposes/converts ----------------

#define ZB 391     // ceil(100096/256) zero blocks
#define WB1 256    // 256*256/256
#define WB2 128
#define WB3 64

__global__ void setup_kernel(float* __restrict__ zp,
                             const float* __restrict__ wg1, const float* __restrict__ ws1,
                             unsigned short* __restrict__ Wt1,
                             const float* __restrict__ wg2, const float* __restrict__ ws2,
                             unsigned short* __restrict__ Wt2,
                             const float* __restrict__ wg3, const float* __restrict__ ws3,
                             unsigned short* __restrict__ Wt3) {
    int b = blockIdx.x;
    int t = threadIdx.x;
    if (b < ZB) {
        int i = b * 256 + t;
        if (i < 100096) zp[i] = 0.f;
    } else if (b < ZB + WB1) {
        int idx = (b - ZB) * 256 + t;       // [0, 65536)
        int n = idx >> 8, k = idx & 255;    // K=256, Fo=128, N2=256
        float v = (n < 128) ? wg1[(size_t)k * 128 + n]
                            : ws1[(size_t)k * 128 + (n - 128)];
        Wt1[idx] = f2b(v);
    } else if (b < ZB + WB1 + WB2) {
        int idx = (b - ZB - WB1) * 256 + t; // [0, 32768)
        int n = idx >> 7, k = idx & 127;    // K=128, Fo=128, N2=256
        float v = (n < 128) ? wg2[(size_t)k * 128 + n]
                            : ws2[(size_t)k * 128 + (n - 128)];
        Wt2[idx] = f2b(v);
    } else {
        int idx = (b - ZB - WB1 - WB2) * 256 + t; // [0, 16384)
        int n = idx >> 7, k = idx & 127;          // K=128, Fo=40, N2=128
        float v = 0.f;
        if (n < 40) v = wg3[(size_t)k * 40 + n];
        else if (n < 80) v = ws3[(size_t)k * 40 + (n - 40)];
        Wt3[idx] = f2b(v);
    }
}

// ---------------- MFMA dual GEMM body (bf16 or fp32-A staging) ----------------

template <bool AF32>
__device__ __forceinline__ void gemm_body(int bx, int by, const void* __restrict__ Av,
                                          const unsigned short* __restrict__ Wt,
                                          const float* __restrict__ bias,
                                          unsigned short* __restrict__ Cg,
                                          unsigned short* __restrict__ Cs,
                                          int M, int K, int Fo,
                                          unsigned short* sA, unsigned short* sB) {
    const int t = threadIdx.x;
    const int lane = t & 63;
    const int wave = t >> 6;
    const int wm = wave >> 1, wn = wave & 1;
    const int l15 = lane & 15, quad = lane >> 4;
    const int row0 = bx * 128;
    const int colbase = by * 128;

    fx4 acc[4][4];
#pragma unroll
    for (int r = 0; r < 4; ++r)
#pragma unroll
        for (int c = 0; c < 4; ++c) acc[r][c] = (fx4){0.f, 0.f, 0.f, 0.f};

    for (int kc = 0; kc < K; kc += 64) {
#pragma unroll
        for (int j = 0; j < 4; ++j) {
            int c = wave * 4 + j;
            int rb = c >> 1, kh = c & 1;
            int ar = row0 + rb * 16 + l15;
            if (ar >= M) ar = M - 1;
            int ak = kc + kh * 32 + quad * 8;
            if constexpr (AF32) {
                // fp32 A: load 8 floats, convert to bf16, manual LDS write
                // (same layout as the DMA path: base + lane*16B)
                const float* Af = (const float*)Av;
                const float4* p = (const float4*)(Af + (size_t)ar * K + ak);
                float4 v0 = p[0], v1 = p[1];
                uint4 u;
                u.x = pack2(v0.x, v0.y);
                u.y = pack2(v0.z, v0.w);
                u.z = pack2(v1.x, v1.y);
                u.w = pack2(v1.z, v1.w);
                *reinterpret_cast<uint4*>(sA + c * 512 + lane * 8) = u;
            } else {
                gload_lds16((const unsigned short*)Av + (size_t)ar * K + ak, sA + c * 512);
            }
            int br = colbase + rb * 16 + l15;
            gload_lds16(Wt + (size_t)br * K + ak, sB + c * 512);
        }
        __syncthreads();

#pragma unroll
        for (int kh = 0; kh < 2; ++kh) {
            short8 a[4], b[4];
#pragma unroll
            for (int r = 0; r < 4; ++r)
                a[r] = *reinterpret_cast<const short8*>(&sA[((wm * 4 + r) * 2 + kh) * 512 + lane * 8]);
#pragma unroll
            for (int c = 0; c < 4; ++c)
                b[c] = *reinterpret_cast<const short8*>(&sB[((wn * 4 + c) * 2 + kh) * 512 + lane * 8]);
#pragma unroll
            for (int r = 0; r < 4; ++r)
#pragma unroll
                for (int c = 0; c < 4; ++c)
                    acc[r][c] = __builtin_amdgcn_mfma_f32_16x16x32_bf16(a[r], b[c], acc[r][c], 0, 0, 0);
        }
        __syncthreads();
    }

#pragma unroll
    for (int c = 0; c < 4; ++c) {
        int f = colbase + wn * 64 + c * 16 + l15;
        if (f >= 2 * Fo) continue;
        bool isG = (f < Fo);
        int col = isG ? f : f - Fo;
        float badd = isG ? 0.f : bias[col];
        unsigned short* base = isG ? Cg : Cs;
#pragma unroll
        for (int r = 0; r < 4; ++r) {
#pragma unroll
            for (int reg = 0; reg < 4; ++reg) {
                int row = row0 + wm * 64 + r * 16 + quad * 4 + reg;
                if (row < M) base[(size_t)row * Fo + col] = f2b(acc[r][c][reg] + badd);
            }
        }
    }
}

// ---------------- fused: edge-count atomics + layer-1 GEMM ----------------
// Atomic blocks first (TCC-atomic-bound long pole); gemm1 blocks co-schedule
// into the idle MFMA/VALU/HBM pipes (m114 overlap). gemm1 is independent of
// the CSR chain, so this hides its entire dispatch.

#define CB 3907    // ceil(EE/256) atomic blocks
#define GX1 391    // (NN+127)/128 gemm x-blocks (y=2)

__global__ __launch_bounds__(256) void pre2_kernel(
    const int* __restrict__ ei, const float* __restrict__ ew,
    unsigned long long* __restrict__ cnt64, unsigned* __restrict__ rank,
    const float* __restrict__ x, const unsigned short* __restrict__ Wt1,
    const float* __restrict__ bias1,
    unsigned short* __restrict__ Cg, unsigned short* __restrict__ Cs) {
    __shared__ unsigned short sA[128 * 64];
    __shared__ unsigned short sB[128 * 64];
    int b = blockIdx.x;
    if (b < CB) {
        int e = b * 256 + threadIdx.x;
        if (e < EE) {
            int d = ei[EE + e];
            unsigned fx = __float2uint_rn(ew[e] * FIXSCALE);
            unsigned long long old =
                atomicAdd(&cnt64[d], 0x100000000ull | (unsigned long long)fx);
            rank[e] = (unsigned)(old >> 32);
        }
        return;
    }
    int gi = b - CB;
    int by = gi / GX1;
    int bx = gi - by * GX1;
    gemm_body<true>(bx, by, x, Wt1, bias1, Cg, Cs, NN, 256, 128, sA, sB);
}

// standalone GEMM for layers 2/3 (bf16 A)
template <bool AF32>
__global__ __launch_bounds__(256) void gemm_mfma(const void* __restrict__ Ab,
                                                 const unsigned short* __restrict__ Wt,
                                                 const float* __restrict__ bias,
                                                 unsigned short* __restrict__ Cg,
                                                 unsigned short* __restrict__ Cs,
                                                 int M, int K, int Fo) {
    __shared__ unsigned short sA[128 * 64];
    __shared__ unsigned short sB[128 * 64];
    gemm_body<AF32>(blockIdx.x, blockIdx.y, Ab, Wt, bias, Cg, Cs, M, K, Fo, sA, sB);
}

// ---------------- CSR build ----------------

__global__ __launch_bounds__(1024) void dinvsum_kernel(const uint2* __restrict__ cnt64,
                                                       float* __restrict__ dinv,
                                                       int* __restrict__ bsum) {
    __shared__ int s[1024];
    const int t = threadIdx.x;
    int idx = blockIdx.x * 1024 + t;
    uint2 cv = make_uint2(0u, 0u);
    if (idx < NN) cv = cnt64[idx];
    float deg = (float)cv.x * (1.f / FIXSCALE);
    if (idx < NN) dinv[idx] = (deg > 0.f) ? rsqrtf(deg) : 0.f;
    s[t] = (int)cv.y;
    __syncthreads();
#pragma unroll
    for (int off = 512; off > 0; off >>= 1) {
        if (t < off) s[t] += s[t + off];
        __syncthreads();
    }
    if (t == 0) bsum[blockIdx.x] = s[0];
}

__global__ __launch_bounds__(64) void scanB_kernel(const int* __restrict__ bsum,
                                                   int* __restrict__ bpre, int nb) {
    int t = threadIdx.x;
    int v = (t < nb) ? bsum[t] : 0;
    int own = v;
#pragma unroll
    for (int off = 1; off < 64; off <<= 1) {
        int u = __shfl_up(v, off);
        if (t >= off) v += u;
    }
    if (t < nb) bpre[t] = v - own;
}

__global__ __launch_bounds__(1024) void scanC_kernel(const uint2* __restrict__ cnt64,
                                                     const int* __restrict__ bpre,
                                                     int* __restrict__ rowstart) {
    __shared__ int s[1024];
    const int t = threadIdx.x;
    int idx = blockIdx.x * 1024 + t;
    int v = (idx < NN) ? (int)cnt64[idx].y : 0;
    s[t] = v;
    __syncthreads();
#pragma unroll
    for (int off = 1; off < 1024; off <<= 1) {
        int u = (t >= off) ? s[t - off] : 0;
        __syncthreads();
        s[t] += u;
        __syncthreads();
    }
    if (idx < NN) rowstart[idx] = s[t] - v + bpre[blockIdx.x];
    if (idx == 0) rowstart[NN] = EE;
}

// atomic-free scatter: 4-byte records (src:16 | w:bf16)
__global__ void fill_kernel(const int* __restrict__ ei, const float* __restrict__ ew,
                            const float* __restrict__ dinv, const int* __restrict__ rowstart,
                            const unsigned* __restrict__ rank, unsigned* __restrict__ eprec4) {
    int e = blockIdx.x * blockDim.x + threadIdx.x;
    if (e >= EE) return;
    int s = ei[e], d = ei[EE + e];
    int idx = rowstart[d] + (int)rank[e];
    float w = dinv[s] * ew[e] * dinv[d];
    eprec4[idx] = ((unsigned)s << 16) | (unsigned)f2b(w);
}

// ---------------- pull aggregation + fused BN/ReLU, Fo=128 ----------------

template <bool RELU>
__global__ __launch_bounds__(256) void agg128_kernel(
    const int* __restrict__ rowstart, const unsigned* __restrict__ eprec4,
    const unsigned* __restrict__ hw, const unsigned* __restrict__ selfC,
    const float* __restrict__ g, const float* __restrict__ be,
    const float* __restrict__ mu, const float* __restrict__ va,
    unsigned* __restrict__ out) {
    int wave = threadIdx.x >> 6;
    int lane = threadIdx.x & 63;
    int n = blockIdx.x * 4 + wave;
    if (n >= NN) return;
    unsigned scp = selfC[n * 64 + lane];
    float acc0 = blo(scp), acc1 = bhi(scp);
    int beg = rowstart[n], end = rowstart[n + 1];
    int i = beg;
    for (; i + 4 <= end; i += 4) {
        unsigned e0 = eprec4[i], e1 = eprec4[i + 1], e2 = eprec4[i + 2], e3 = eprec4[i + 3];
        unsigned v0 = hw[(e0 >> 16) * 64u + lane];
        unsigned v1 = hw[(e1 >> 16) * 64u + lane];
        unsigned v2 = hw[(e2 >> 16) * 64u + lane];
        unsigned v3 = hw[(e3 >> 16) * 64u + lane];
        float w0 = blo(e0), w1 = blo(e1), w2 = blo(e2), w3 = blo(e3);
        acc0 += blo(v0) * w0; acc1 += bhi(v0) * w0;
        acc0 += blo(v1) * w1; acc1 += bhi(v1) * w1;
        acc0 += blo(v2) * w2; acc1 += bhi(v2) * w2;
        acc0 += blo(v3) * w3; acc1 += bhi(v3) * w3;
    }
    for (; i < end; ++i) {
        unsigned e = eprec4[i];
        unsigned v = hw[(e >> 16) * 64u + lane];
        float w = blo(e);
        acc0 += blo(v) * w; acc1 += bhi(v) * w;
    }
    float2 m2 = reinterpret_cast<const float2*>(mu)[lane];
    float2 v2f = reinterpret_cast<const float2*>(va)[lane];
    float2 g2 = reinterpret_cast<const float2*>(g)[lane];
    float2 b2 = reinterpret_cast<const float2*>(be)[lane];
    float r0 = (acc0 - m2.x) * rsqrtf(v2f.x + EPSV) * g2.x + b2.x;
    float r1 = (acc1 - m2.y) * rsqrtf(v2f.y + EPSV) * g2.y + b2.y;
    if (RELU) {
        r0 = fmaxf(r0, 0.f);
        r1 = fmaxf(r1, 0.f);
    }
    out[n * 64 + lane] = pack2(r0, r1);
}

// ---------------- final layer aggregation, Fo=40, fp32 out ----------------

__global__ __launch_bounds__(256) void agg40_kernel(
    const int* __restrict__ rowstart, const unsigned* __restrict__ eprec4,
    const unsigned* __restrict__ hw, const unsigned* __restrict__ selfC,
    const float* __restrict__ g, const float* __restrict__ be,
    const float* __restrict__ mu, const float* __restrict__ va,
    float* __restrict__ out) {
    int wave = threadIdx.x >> 6;
    int lane = threadIdx.x & 63;
    int n = blockIdx.x * 4 + wave;
    if (n >= NN) return;
    int grp = lane / 20;
    int fl = lane - grp * 20;
    float acc0 = 0.f, acc1 = 0.f;
    int beg = rowstart[n], end = rowstart[n + 1];
    if (grp < 3) {
        for (int i = beg + grp; i < end; i += 3) {
            unsigned e = eprec4[i];
            unsigned v = hw[(e >> 16) * 20u + fl];
            float w = blo(e);
            acc0 += blo(v) * w;
            acc1 += bhi(v) * w;
        }
    }
    acc0 += __shfl(acc0, lane + 20) + __shfl(acc0, lane + 40);
    acc1 += __shfl(acc1, lane + 20) + __shfl(acc1, lane + 40);
    if (lane < 20) {
        int f0 = lane * 2;
        unsigned scp = selfC[n * 20 + lane];
        acc0 += blo(scp);
        acc1 += bhi(scp);
        float2 m2 = reinterpret_cast<const float2*>(mu)[lane];
        float2 v2f = reinterpret_cast<const float2*>(va)[lane];
        float2 g2 = reinterpret_cast<const float2*>(g)[lane];
        float2 b2 = reinterpret_cast<const float2*>(be)[lane];
        float r0 = (acc0 - m2.x) * rsqrtf(v2f.x + EPSV) * g2.x + b2.x;
        float r1 = (acc1 - m2.y) * rsqrtf(v2f.y + EPSV) * g2.y + b2.y;
        *reinterpret_cast<float2*>(&out[(size_t)n * 40 + f0]) = make_float2(r0, r1);
    }
}

// ---------------- launch ----------------

extern "C" void kernel_launch(void* const* d_in, const int* in_sizes, int n_in,
                              void* d_out, int out_size, void* d_ws, size_t ws_size,
                              hipStream_t stream) {
    const float* x = (const float*)d_in[0];
    const int* ei = (const int*)d_in[1];
    const float* ew = (const float*)d_in[2];

    const float* wg[3]  = {(const float*)d_in[3],  (const float*)d_in[10], (const float*)d_in[17]};
    const float* wsf[3] = {(const float*)d_in[4],  (const float*)d_in[11], (const float*)d_in[18]};
    const float* bs[3]  = {(const float*)d_in[5],  (const float*)d_in[12], (const float*)d_in[19]};
    const float* gm[3]  = {(const float*)d_in[6],  (const float*)d_in[13], (const float*)d_in[20]};
    const float* bt[3]  = {(const float*)d_in[7],  (const float*)d_in[14], (const float*)d_in[21]};
    const float* mu[3]  = {(const float*)d_in[8],  (const float*)d_in[15], (const float*)d_in[22]};
    const float* vr[3]  = {(const float*)d_in[9],  (const float*)d_in[16], (const float*)d_in[23]};

    // workspace layout (float-sized slots), regions disjoint
    float* W = (float*)d_ws;
    unsigned long long* cnt64 = (unsigned long long*)W;       // [0, 100096)
    float* dinv     = W + 100096;                 // [100096, 150144)
    unsigned* rank  = (unsigned*)(W + 150144);    // [150144, 1150144)
    int*   bsum     = (int*)(W + 1150144);        // [1150144, 1150208)
    int*   bpre     = (int*)(W + 1150208);        // [1150208, 1150272)
    int*   rowstart = (int*)(W + 1150272);        // [1150272, 1200384)
    unsigned* eprec4 = (unsigned*)(W + 1200384);  // [1200384, 2200384)
    unsigned short* Wt1 = (unsigned short*)(W + 2200384);     // [2200384, 2233152)
    unsigned short* Wt2 = (unsigned short*)(W + 2233152);     // [2233152, 2249536)
    unsigned short* Wt3 = (unsigned short*)(W + 2249536);     // [2249536, 2257728)
    unsigned short* bufH = (unsigned short*)(W + 2257728);    // [2257728, 8657728)
    unsigned short* bufHW = (unsigned short*)(W + 8657728);   // [8657728, 11857728)
    unsigned short* bufSb = (unsigned short*)(W + 11857728);  // [11857728, 15057728)

    const int B = 256;
    const int SB = 49;

    // setup: zero cnt64 + weight conversions (tiny, BW-trivial)
    setup_kernel<<<ZB + WB1 + WB2 + WB3, B, 0, stream>>>(
        W, wg[0], wsf[0], Wt1, wg[1], wsf[1], Wt2, wg[2], wsf[2], Wt3);

    // fused: edge atomics (long pole) + layer-1 GEMM (fp32 A, hidden in shadow)
    pre2_kernel<<<CB + 2 * GX1, B, 0, stream>>>(
        ei, ew, cnt64, rank, x, Wt1, bs[0], bufHW, bufSb);

    dinvsum_kernel<<<SB, 1024, 0, stream>>>((const uint2*)cnt64, dinv, bsum);
    scanB_kernel<<<1, 64, 0, stream>>>(bsum, bpre, SB);
    scanC_kernel<<<SB, 1024, 0, stream>>>((const uint2*)cnt64, bpre, rowstart);
    fill_kernel<<<(EE + B - 1) / B, B, 0, stream>>>(ei, ew, dinv, rowstart, rank, eprec4);

    const int aggGrid = (NN + 3) / 4;
    dim3 g2((NN + 127) / 128, 2), g1((NN + 127) / 128, 1);

    // layer 1 aggregation (gemm1 already done inside pre2)
    agg128_kernel<true><<<aggGrid, B, 0, stream>>>(rowstart, eprec4, (const unsigned*)bufHW,
                                                   (const unsigned*)bufSb, gm[0], bt[0], mu[0], vr[0],
                                                   (unsigned*)bufH);

    // layer 2: h bf16 [N,128] -> 128
    gemm_mfma<false><<<g2, B, 0, stream>>>(bufH, Wt2, bs[1], bufHW, bufSb, NN, 128, 128);
    agg128_kernel<true><<<aggGrid, B, 0, stream>>>(rowstart, eprec4, (const unsigned*)bufHW,
                                                   (const unsigned*)bufSb, gm[1], bt[1], mu[1], vr[1],
                                                   (unsigned*)bufH);

    // layer 3: h bf16 [N,128] -> 40 (cols padded to 128), fp32 out
    gemm_mfma<false><<<g1, B, 0, stream>>>(bufH, Wt3, bs[2], bufHW, bufSb, NN, 128, 40);
    agg40_kernel<<<aggGrid, B, 0, stream>>>(rowstart, eprec4, (const unsigned*)bufHW,
                                            (const unsigned*)bufSb, gm[2], bt[2], mu[2], vr[2],
                                            (float*)d_out);
}